// Round 4
// baseline (1610.056 us; speedup 1.0000x reference)
//
#include <hip/hip_runtime.h>

// DINOMIMICClassification: per-sample 3-layer expert MLP (E=16,B=512,D=1536,H=768,T=2).
// R4: pure-streaming grouped GEMM. Lane = one W column; W streamed global->VGPR via a
// 16-deep prefetch ring (no barriers, no W LDS); X transposed in LDS, broadcast-read
// b128; acc[samples] in VGPRs with compile-time NQ via switch. W read exactly once.

namespace {
constexpr int NE = 16, NB = 512, ND = 1536, NH = 768;
constexpr int NSP  = 48;   // max samples per pass (acc registers)
constexpr int XPAD = 52;   // Xs row stride in floats: 16B-aligned rows, bank-spread
constexpr int KS1 = 8, KCH1 = ND / KS1;   // 192
constexpr int KS2 = 4, KCH2 = NH / KS2;   // 192

template<int NQ, int KCH>
__device__ __forceinline__ void kloop_store(
    const float* __restrict__ Wc,              // &W[e][k0][c] (stride NH)
    const float (* __restrict__ Xs)[XPAD],
    const int* __restrict__ lst, int s0, int n,
    float* __restrict__ outp)                  // part + ks*NB*NH + c
{
    float acc[NQ * 8];
    #pragma unroll
    for (int i = 0; i < NQ * 8; ++i) acc[i] = 0.f;

    float pf[16];
    #pragma unroll
    for (int i = 0; i < 16; ++i) pf[i] = Wc[(size_t)i * NH];

    #pragma unroll 1
    for (int kb = 0; kb < KCH; kb += 16) {
        #pragma unroll
        for (int u = 0; u < 16; ++u) {
            const float wv = pf[u];
            const int kn = kb + 16 + u;
            if (kn < KCH) pf[u] = Wc[(size_t)kn * NH];   // keep ring full (issues early)
            const float* xr = Xs[kb + u];
            #pragma unroll
            for (int q = 0; q < NQ; ++q) {
                const float4 x0 = *(const float4*)(xr + q * 8);
                const float4 x1 = *(const float4*)(xr + q * 8 + 4);
                acc[q*8+0] += wv * x0.x; acc[q*8+1] += wv * x0.y;
                acc[q*8+2] += wv * x0.z; acc[q*8+3] += wv * x0.w;
                acc[q*8+4] += wv * x1.x; acc[q*8+5] += wv * x1.y;
                acc[q*8+6] += wv * x1.z; acc[q*8+7] += wv * x1.w;
            }
        }
    }
    #pragma unroll
    for (int i = 0; i < NQ * 8; ++i) {
        const int s = s0 + i;
        if (s < n) outp[(size_t)lst[s] * NH] = acc[i];
    }
}

// part[ks][b][c] = sum_{k in split ks} act[b][k] * W[e_b][k][c]
template<int DIN, int KSN, int KCH, int CW>
__global__ __launch_bounds__(CW, 2)
void stream_mm(const float* __restrict__ act,   // [NB][DIN]
               const int*   __restrict__ head_idx,
               const float* __restrict__ W,     // [NE][DIN][NH]
               float*       __restrict__ part)  // [KSN][NB][NH]
{
    constexpr int NCQ = NH / CW;
    const int bid = blockIdx.x;
    const int e   = bid / (NCQ * KSN);
    const int rem = bid % (NCQ * KSN);
    const int cq  = rem / KSN;
    const int ks  = rem % KSN;
    const int tid = threadIdx.x;

    __shared__ int   lst[NB];
    __shared__ int   n_sh;
    __shared__ float Xs[KCH][XPAD];

    if (tid < 64) {   // wave 0: ballot-compact this expert's sample list
        int cnt = 0;
        for (int base = 0; base < NB; base += 64) {
            const int h = head_idx[base + tid];
            const unsigned long long m = __ballot(h == e);
            const int pos = cnt + __popcll(m & ((1ull << tid) - 1ull));
            if (h == e) lst[pos] = base + tid;
            cnt += __popcll(m);
        }
        if (tid == 0) n_sh = cnt;
    }
    __syncthreads();
    const int n = n_sh;
    if (n == 0) return;

    const int c  = cq * CW + tid;       // this thread's output column
    const int k0 = ks * KCH;
    const float* Wc   = W + ((size_t)e * DIN + k0) * NH + c;
    float*       outp = part + (size_t)ks * NB * NH + c;

    for (int s0 = 0; s0 < n; s0 += NSP) {
        __syncthreads();   // protect Xs from previous pass readers
        constexpr int C4 = KCH / 4;
        for (int idx = tid; idx < NSP * C4; idx += CW) {
            const int s  = idx / C4;
            const int c4 = idx % C4;
            if (s0 + s < n) {
                const float4 v = *(const float4*)(act + (size_t)lst[s0 + s] * DIN + k0 + c4 * 4);
                Xs[c4*4+0][s] = v.x; Xs[c4*4+1][s] = v.y;
                Xs[c4*4+2][s] = v.z; Xs[c4*4+3][s] = v.w;
            }
            // s >= n: leave garbage; those acc lanes are never stored
        }
        __syncthreads();

        const int m  = (n - s0) < NSP ? (n - s0) : NSP;
        const int nq = (m + 7) >> 3;
        switch (nq) {
            case 1: kloop_store<1, KCH>(Wc, Xs, lst, s0, n, outp); break;
            case 2: kloop_store<2, KCH>(Wc, Xs, lst, s0, n, outp); break;
            case 3: kloop_store<3, KCH>(Wc, Xs, lst, s0, n, outp); break;
            case 4: kloop_store<4, KCH>(Wc, Xs, lst, s0, n, outp); break;
            case 5: kloop_store<5, KCH>(Wc, Xs, lst, s0, n, outp); break;
            default: kloop_store<6, KCH>(Wc, Xs, lst, s0, n, outp); break;
        }
    }
}

// h1[b][c] = relu(b1[e_b][c] + sum_ks part[ks][b][c])
template<int KSN>
__global__ __launch_bounds__(256)
void combine_relu(const float* __restrict__ part,   // [KSN][NB][NH]
                  const float* __restrict__ bias,   // [NE][NH]
                  const int*   __restrict__ head_idx,
                  float*       __restrict__ outp)   // [NB][NH]
{
    const int i = blockIdx.x * 256 + threadIdx.x;    // float4 index
    if (i >= NB * NH / 4) return;
    const int b  = i / (NH / 4);
    const int c4 = i % (NH / 4);
    constexpr int STR = NB * NH / 4;
    const float4* P = (const float4*)part;
    const int e = head_idx[b];
    const float4 bb = ((const float4*)bias)[e * (NH / 4) + c4];
    float sx = bb.x, sy = bb.y, sz = bb.z, sw = bb.w;
    #pragma unroll
    for (int ks = 0; ks < KSN; ++ks) {
        const float4 v = P[i + ks * STR];
        sx += v.x; sy += v.y; sz += v.z; sw += v.w;
    }
    float4 o;
    o.x = fmaxf(sx, 0.f); o.y = fmaxf(sy, 0.f);
    o.z = fmaxf(sz, 0.f); o.w = fmaxf(sw, 0.f);
    ((float4*)outp)[i] = o;
}

// out[b][t] = relu(sum_ks h2p[ks][b][:] + b2[e]) . W3[e][:,t] + b3[e][t]
template<int KSN>
__global__ __launch_bounds__(256)
void final_head(const float* __restrict__ h2p,  // [KSN][NB][NH]
                const float* __restrict__ b2,   // [NE][NH]
                const float* __restrict__ W3,   // [NE][NH][2]
                const float* __restrict__ b3,   // [NE][2]
                const int*   __restrict__ head_idx,
                float*       __restrict__ out)  // [NB][2]
{
    const int b    = blockIdx.x * 4 + (threadIdx.x >> 6);
    const int lane = threadIdx.x & 63;
    const int e    = head_idx[b];
    constexpr size_t STR = (size_t)NB * NH;
    float a0 = 0.f, a1 = 0.f;
    for (int h = lane; h < NH; h += 64) {
        const size_t o = (size_t)b * NH + h;
        float s = b2[e * NH + h];
        #pragma unroll
        for (int ks = 0; ks < KSN; ++ks) s += h2p[ks * STR + o];
        s = fmaxf(s, 0.f);
        const float2 w = *(const float2*)&W3[((size_t)e * NH + h) * 2];
        a0 += s * w.x;
        a1 += s * w.y;
    }
    #pragma unroll
    for (int off = 32; off > 0; off >>= 1) {
        a0 += __shfl_down(a0, off);
        a1 += __shfl_down(a1, off);
    }
    if (lane == 0) {
        out[b * 2 + 0] = a0 + b3[e * 2 + 0];
        out[b * 2 + 1] = a1 + b3[e * 2 + 1];
    }
}
} // namespace

extern "C" void kernel_launch(void* const* d_in, const int* in_sizes, int n_in,
                              void* d_out, int out_size, void* d_ws, size_t ws_size,
                              hipStream_t stream) {
    const float* x   = (const float*)d_in[0];
    const int*   hi  = (const int*)  d_in[1];
    const float* W1  = (const float*)d_in[2];
    const float* b1  = (const float*)d_in[3];
    const float* W2  = (const float*)d_in[4];
    const float* b2  = (const float*)d_in[5];
    const float* W3  = (const float*)d_in[6];
    const float* b3  = (const float*)d_in[7];
    float* out = (float*)d_out;

    // ws (fp32): h1p [KS1][B][H] 12.6MB (reused as h2p [KS2][B][H] 6.3MB) | h1 [B][H] 1.5MB
    float* h1p = (float*)d_ws;
    float* h1  = h1p + (size_t)KS1 * NB * NH;
    float* h2p = h1p;   // alias: h1p dead after combine_relu

    stream_mm<ND, KS1, KCH1, 256><<<NE * (NH/256) * KS1, 256, 0, stream>>>(x,  hi, W1, h1p);
    combine_relu<KS1><<<(NB * NH / 4 + 255) / 256, 256, 0, stream>>>(h1p, b1, hi, h1);
    stream_mm<NH, KS2, KCH2, 128><<<NE * (NH/128) * KS2, 128, 0, stream>>>(h1, hi, W2, h2p);
    final_head<KS2><<<NB / 4, 256, 0, stream>>>(h2p, b2, W3, b3, hi, out);
}

// Round 5
// 1036.950 us; speedup vs baseline: 1.5527x; 1.5527x over previous
//
#include <hip/hip_runtime.h>

// DINOMIMICClassification: per-sample 3-layer expert MLP (E=16,B=512,D=1536,H=768,T=2).
// R5: back to the proven R0 tile structure (52us, 0 conflicts, VGPR 40), fixing its
// one measured problem (barrier-latency stalls, VALUBusy 33%) with register-staged
// double buffering: issue stage t+1 global loads -> regs BEFORE compute(t), ds_write
// after the barrier (T14). W read exactly once. Pass width adapts (32/64 samples)
// to the expert group size to halve FMA waste at n~32.
// R4 lesson: no big runtime-indexed register arrays; acc is [SPT][4], statically indexed.

namespace {
constexpr int NE = 16, NB = 512, ND = 1536, NH = 768;
constexpr int CT = 64;            // cols per block tile
constexpr int KT = 32;            // k rows per LDS stage
constexpr int NCT = NH / CT;      // 12
constexpr int KS1 = 8, KS2 = 4;   // k-splits (KLEN = 192 for both layers)
constexpr int KLEN = 192;
template<int N> struct IC { static constexpr int value = N; };

// part[ks][b][c0+cg*4..+3] = sum_{k in split ks} act[b][k] * W[e_b][k][c]
template<int DIN, int KSN>
__global__ __launch_bounds__(256, 6)
void tile_mm(const float* __restrict__ act,   // [NB][DIN]
             const int*   __restrict__ head_idx,
             const float* __restrict__ W,     // [NE][DIN][NH]
             float*       __restrict__ part)  // [KSN][NB][NH]
{
    static_assert(DIN / KSN == KLEN, "KLEN mismatch");
    constexpr int NST = KLEN / KT;  // 6 stages
    const int bid = blockIdx.x;
    const int e   = bid / (NCT * KSN);
    const int rem = bid % (NCT * KSN);
    const int j   = rem / KSN;
    const int ks  = rem % KSN;
    const int tid = threadIdx.x;

    __shared__ int lst[NB];
    __shared__ int n_sh;
    if (tid < 64) {   // wave 0: ballot-compact this expert's sample list
        int cnt = 0;
        for (int base = 0; base < NB; base += 64) {
            const int h = head_idx[base + tid];
            const unsigned long long m = __ballot(h == e);
            const int pos = cnt + __popcll(m & ((1ull << tid) - 1ull));
            if (h == e) lst[pos] = base + tid;
            cnt += __popcll(m);
        }
        if (tid == 0) n_sh = cnt;
    }
    __syncthreads();
    const int n = n_sh;
    if (n == 0) return;

    __shared__ float Ws[KT][CT];   // 8KB  [k][c]
    __shared__ float Xs[KT][64];   // 8KB  [k][s] transposed

    const int cg = tid & 15;            // compute: 4-col group
    const int sg = tid >> 4;            // compute: sample group (0..15)
    const int c0 = j * CT, k0 = ks * KLEN;
    const float* Wp = W + ((size_t)e * DIN + k0) * NH + c0;
    const int w_kk = tid >> 4;          // W stage: rows w_kk, w_kk+16
    const int w_cc = (tid & 15) * 4;    //          cols w_cc..+3
    const int x_s  = tid & 63;          // X stage: sample slot
    const int x_kh = tid >> 6;          //          k-octet (0..3)
    float* po = part + (size_t)ks * NB * NH + c0 + cg * 4;

    for (int s0 = 0; s0 < n; s0 += 64) {
        const int m = n - s0;
        auto do_pass = [&](auto sptc) {
            constexpr int SPT = decltype(sptc)::value;   // samples per thread (2 or 4)
            float4 rw0, rw1, rx0, rx1;                   // staging registers
            auto issue = [&](int kt) {                   // global -> regs (no LDS dep)
                const float* g = Wp + (size_t)(kt + w_kk) * NH + w_cc;
                rw0 = *(const float4*)g;
                rw1 = *(const float4*)(g + (size_t)16 * NH);
                if (s0 + x_s < n) {
                    const float* ga = act + (size_t)lst[s0 + x_s] * DIN + k0 + kt + x_kh * 8;
                    rx0 = *(const float4*)ga;
                    rx1 = *(const float4*)(ga + 4);
                } else {
                    rx0 = make_float4(0.f, 0.f, 0.f, 0.f);
                    rx1 = rx0;
                }
            };
            auto commit = [&]() {                        // regs -> LDS
                *(float4*)&Ws[w_kk][w_cc]      = rw0;
                *(float4*)&Ws[w_kk + 16][w_cc] = rw1;
                Xs[x_kh*8+0][x_s] = rx0.x; Xs[x_kh*8+1][x_s] = rx0.y;
                Xs[x_kh*8+2][x_s] = rx0.z; Xs[x_kh*8+3][x_s] = rx0.w;
                Xs[x_kh*8+4][x_s] = rx1.x; Xs[x_kh*8+5][x_s] = rx1.y;
                Xs[x_kh*8+6][x_s] = rx1.z; Xs[x_kh*8+7][x_s] = rx1.w;
            };

            float acc[SPT][4];
            #pragma unroll
            for (int i = 0; i < SPT; ++i)
                #pragma unroll
                for (int q = 0; q < 4; ++q) acc[i][q] = 0.f;

            issue(0);
            __syncthreads();   // previous pass readers done with LDS
            commit();
            __syncthreads();

            for (int t = 0; t < NST; ++t) {
                if (t + 1 < NST) issue((t + 1) * KT);    // in flight during compute
                #pragma unroll
                for (int k = 0; k < KT; ++k) {
                    const float4 wv = *(const float4*)&Ws[k][cg * 4];
                    if constexpr (SPT == 2) {
                        const float2 xv = *(const float2*)&Xs[k][sg * 2];
                        acc[0][0] += xv.x*wv.x; acc[0][1] += xv.x*wv.y;
                        acc[0][2] += xv.x*wv.z; acc[0][3] += xv.x*wv.w;
                        acc[1][0] += xv.y*wv.x; acc[1][1] += xv.y*wv.y;
                        acc[1][2] += xv.y*wv.z; acc[1][3] += xv.y*wv.w;
                    } else {
                        const float4 xv = *(const float4*)&Xs[k][sg * 4];
                        acc[0][0] += xv.x*wv.x; acc[0][1] += xv.x*wv.y; acc[0][2] += xv.x*wv.z; acc[0][3] += xv.x*wv.w;
                        acc[1][0] += xv.y*wv.x; acc[1][1] += xv.y*wv.y; acc[1][2] += xv.y*wv.z; acc[1][3] += xv.y*wv.w;
                        acc[2][0] += xv.z*wv.x; acc[2][1] += xv.z*wv.y; acc[2][2] += xv.z*wv.z; acc[2][3] += xv.z*wv.w;
                        acc[3][0] += xv.w*wv.x; acc[3][1] += xv.w*wv.y; acc[3][2] += xv.w*wv.z; acc[3][3] += xv.w*wv.w;
                    }
                }
                if (t + 1 < NST) {
                    __syncthreads();   // everyone done reading stage t
                    commit();          // vmcnt waited here, ~1000cy after issue
                    __syncthreads();   // stage t+1 visible
                }
            }

            #pragma unroll
            for (int si = 0; si < SPT; ++si) {
                const int s = s0 + sg * SPT + si;
                if (s < n)
                    *(float4*)(po + (size_t)lst[s] * NH) =
                        make_float4(acc[si][0], acc[si][1], acc[si][2], acc[si][3]);
            }
        };
        if (m <= 32) do_pass(IC<2>{}); else do_pass(IC<4>{});
    }
}

// h1[b][c] = relu(b1[e_b][c] + sum_ks part[ks][b][c])
template<int KSN>
__global__ __launch_bounds__(256)
void combine_relu(const float* __restrict__ part,   // [KSN][NB][NH]
                  const float* __restrict__ bias,   // [NE][NH]
                  const int*   __restrict__ head_idx,
                  float*       __restrict__ outp)   // [NB][NH]
{
    const int i = blockIdx.x * 256 + threadIdx.x;    // float4 index
    if (i >= NB * NH / 4) return;
    const int b  = i / (NH / 4);
    const int c4 = i % (NH / 4);
    constexpr int STR = NB * NH / 4;
    const float4* P = (const float4*)part;
    const int e = head_idx[b];
    const float4 bb = ((const float4*)bias)[e * (NH / 4) + c4];
    float sx = bb.x, sy = bb.y, sz = bb.z, sw = bb.w;
    #pragma unroll
    for (int ks = 0; ks < KSN; ++ks) {
        const float4 v = P[i + ks * STR];
        sx += v.x; sy += v.y; sz += v.z; sw += v.w;
    }
    float4 o;
    o.x = fmaxf(sx, 0.f); o.y = fmaxf(sy, 0.f);
    o.z = fmaxf(sz, 0.f); o.w = fmaxf(sw, 0.f);
    ((float4*)outp)[i] = o;
}

// out[b][t] = relu(sum_ks h2p[ks][b][:] + b2[e]) . W3[e][:,t] + b3[e][t]
template<int KSN>
__global__ __launch_bounds__(256)
void final_head(const float* __restrict__ h2p,  // [KSN][NB][NH]
                const float* __restrict__ b2,   // [NE][NH]
                const float* __restrict__ W3,   // [NE][NH][2]
                const float* __restrict__ b3,   // [NE][2]
                const int*   __restrict__ head_idx,
                float*       __restrict__ out)  // [NB][2]
{
    const int b    = blockIdx.x * 4 + (threadIdx.x >> 6);
    const int lane = threadIdx.x & 63;
    const int e    = head_idx[b];
    constexpr size_t STR = (size_t)NB * NH;
    float a0 = 0.f, a1 = 0.f;
    for (int h = lane; h < NH; h += 64) {
        const size_t o = (size_t)b * NH + h;
        float s = b2[e * NH + h];
        #pragma unroll
        for (int ks = 0; ks < KSN; ++ks) s += h2p[ks * STR + o];
        s = fmaxf(s, 0.f);
        const float2 w = *(const float2*)&W3[((size_t)e * NH + h) * 2];
        a0 += s * w.x;
        a1 += s * w.y;
    }
    #pragma unroll
    for (int off = 32; off > 0; off >>= 1) {
        a0 += __shfl_down(a0, off);
        a1 += __shfl_down(a1, off);
    }
    if (lane == 0) {
        out[b * 2 + 0] = a0 + b3[e * 2 + 0];
        out[b * 2 + 1] = a1 + b3[e * 2 + 1];
    }
}
} // namespace

extern "C" void kernel_launch(void* const* d_in, const int* in_sizes, int n_in,
                              void* d_out, int out_size, void* d_ws, size_t ws_size,
                              hipStream_t stream) {
    const float* x   = (const float*)d_in[0];
    const int*   hi  = (const int*)  d_in[1];
    const float* W1  = (const float*)d_in[2];
    const float* b1  = (const float*)d_in[3];
    const float* W2  = (const float*)d_in[4];
    const float* b2  = (const float*)d_in[5];
    const float* W3  = (const float*)d_in[6];
    const float* b3  = (const float*)d_in[7];
    float* out = (float*)d_out;

    // ws (fp32): h1p [KS1][B][H] 12.6MB (reused as h2p [KS2][B][H] 6.3MB) | h1 [B][H] 1.5MB
    float* h1p = (float*)d_ws;
    float* h1  = h1p + (size_t)KS1 * NB * NH;
    float* h2p = h1p;   // alias: h1p dead after combine_relu

    tile_mm<ND, KS1><<<NE * NCT * KS1, 256, 0, stream>>>(x,  hi, W1, h1p);
    combine_relu<KS1><<<(NB * NH / 4 + 255) / 256, 256, 0, stream>>>(h1p, b1, hi, h1);
    tile_mm<NH, KS2><<<NE * NCT * KS2, 256, 0, stream>>>(h1, hi, W2, h2p);
    final_head<KS2><<<NB / 4, 256, 0, stream>>>(h2p, b2, W3, b3, hi, out);
}